// Round 6
// baseline (97.585 us; speedup 1.0000x reference)
//
#include <hip/hip_runtime.h>

typedef float v2f __attribute__((ext_vector_type(2)));

#define THREADS 256
#define ROWS_PER_BLOCK 8
#define NBLOCKS 2048          // 2048 * 8 == 16384 rows
#define DIMS 1024

// tanh on a pair: scalar v_exp/v_rcp (trans pipe), packed VALU elsewhere
__device__ __forceinline__ v2f tanh2(v2f v) {
    v2f vv = v + v;                               // pk_add
    float e0 = __expf(vv.x);                      // mul + v_exp
    float e1 = __expf(vv.y);
    v2f ep = (v2f){e0, e1} + (v2f){1.f, 1.f};     // pk_add
    v2f r = { __builtin_amdgcn_rcpf(ep.x),
              __builtin_amdgcn_rcpf(ep.y) };      // v_rcp x2
    return (v2f){-2.f, -2.f} * r + (v2f){1.f, 1.f}; // pk_fma: t = 1 - 2r
}

// P(t) for two dims at once: 8 v_pk_fma_f32
__device__ __forceinline__ v2f horner9v(v2f t, const v2f* a) {
    v2f p = a[8];
#pragma unroll
    for (int j = 7; j >= 0; --j) p = p * t + a[j]; // contracts to pk_fma
    return p;
}

__global__ __launch_bounds__(THREADS, 4)
void kan_kernel(const float* __restrict__ x,
                const float* __restrict__ coef,
                const float* __restrict__ hw,
                float* __restrict__ out)
{
    const int tid  = threadIdx.x;
    const int lane = tid & 63;
    const int wave = tid >> 6;
    const int d0   = tid * 4;          // this thread owns dims [d0, d0+4)

    // ---- load 36 Chebyshev coefs (dim-major: 9 floats per dim), convert to
    // monomial basis packed over dim-pairs: a2[p][j] = {a_j(dim 2p), a_j(dim 2p+1)} ----
    v2f a2[2][9];
    {
        float cf[36];
        const float4* cp = (const float4*)(coef + (size_t)d0 * 9); // 144 B, 16B aligned
#pragma unroll
        for (int i = 0; i < 9; ++i) {
            float4 v = cp[i];
            cf[4 * i + 0] = v.x; cf[4 * i + 1] = v.y;
            cf[4 * i + 2] = v.z; cf[4 * i + 3] = v.w;
        }
#pragma unroll
        for (int p = 0; p < 2; ++p) {
            const float* cA = cf + 18 * p;      // coefs of dim d0+2p
            const float* cB = cf + 18 * p + 9;  // coefs of dim d0+2p+1
            v2f c[9];
#pragma unroll
            for (int k = 0; k < 9; ++k)
                c[k] = (v2f){cA[k], cB[k]};     // stride-9 pairing (THE fix)
            a2[p][0] = ((c[0] - c[2]) + (c[4] - c[6])) + c[8];
            a2[p][1] = c[1] - 3.f*c[3] + 5.f*c[5] - 7.f*c[7];
            a2[p][2] = 2.f*c[2] - 8.f*c[4] + 18.f*c[6] - 32.f*c[8];
            a2[p][3] = 4.f*c[3] - 20.f*c[5] + 56.f*c[7];
            a2[p][4] = 8.f*c[4] - 48.f*c[6] + 160.f*c[8];
            a2[p][5] = 16.f*c[5] - 112.f*c[7];
            a2[p][6] = 32.f*c[6] - 256.f*c[8];
            a2[p][7] = 64.f*c[7];
            a2[p][8] = 128.f*c[8];
        }
    }

    const int row0 = blockIdx.x * ROWS_PER_BLOCK;

    // ---- issue ALL 8 row loads: 8 outstanding dwordx4 per thread ----
    float4 xv[ROWS_PER_BLOCK];
#pragma unroll
    for (int r = 0; r < ROWS_PER_BLOCK; ++r)
        xv[r] = *(const float4*)(x + (size_t)(row0 + r) * DIMS + d0);

    __shared__ float part[4][ROWS_PER_BLOCK];

#pragma unroll
    for (int g = 0; g < 2; ++g) {
        float s[4];
#pragma unroll
        for (int r = 0; r < 4; ++r) {
            const float4 v = xv[g * 4 + r];
            v2f lo = {v.x, v.y};   // dims d0, d0+1  -> a2[0]
            v2f hi = {v.z, v.w};   // dims d0+2,d0+3 -> a2[1]
            v2f q = horner9v(tanh2(lo), a2[0]) + horner9v(tanh2(hi), a2[1]);
            s[r] = q.x + q.y;
        }
        // 4 butterflies; adds packed 2 rows per pk_add
        v2f u = {s[0], s[1]};
        v2f w = {s[2], s[3]};
#pragma unroll
        for (int off = 32; off >= 1; off >>= 1) {
            v2f us = { __shfl_xor(u.x, off, 64), __shfl_xor(u.y, off, 64) };
            v2f ws = { __shfl_xor(w.x, off, 64), __shfl_xor(w.y, off, 64) };
            u += us;
            w += ws;
        }
        if (lane == 0) {
            part[wave][g * 4 + 0] = u.x;
            part[wave][g * 4 + 1] = u.y;
            part[wave][g * 4 + 2] = w.x;
            part[wave][g * 4 + 3] = w.y;
        }
    }
    __syncthreads();

    if (tid < ROWS_PER_BLOCK) {
        float v = part[0][tid] + part[1][tid] + part[2][tid] + part[3][tid];
        out[row0 + tid] = hw[0] * v;
    }
}

extern "C" void kernel_launch(void* const* d_in, const int* in_sizes, int n_in,
                              void* d_out, int out_size, void* d_ws, size_t ws_size,
                              hipStream_t stream) {
    const float* x    = (const float*)d_in[0];
    const float* coef = (const float*)d_in[1];
    const float* hw   = (const float*)d_in[2];
    // d_in[3] is `degree` (int32) == 8, hard-coded.
    float* out = (float*)d_out;
    kan_kernel<<<NBLOCKS, THREADS, 0, stream>>>(x, coef, hw, out);
}

// Round 9
// 95.630 us; speedup vs baseline: 1.0204x; 1.0204x over previous
//
#include <hip/hip_runtime.h>

typedef float v2f __attribute__((ext_vector_type(2)));

#define THREADS 512
#define ROWS_PER_BLOCK 8
#define NBLOCKS 2048          // 2048 * 8 == 16384 rows
#define DIMS 1024
#define NWAVES (THREADS / 64)

// tanh on a pair: scalar v_exp/v_rcp (trans pipe), packed VALU elsewhere
__device__ __forceinline__ v2f tanh2(v2f v) {
    v2f vv = v + v;
    float e0 = __expf(vv.x);
    float e1 = __expf(vv.y);
    v2f ep = (v2f){e0, e1} + (v2f){1.f, 1.f};
    v2f r = { __builtin_amdgcn_rcpf(ep.x),
              __builtin_amdgcn_rcpf(ep.y) };
    return (v2f){-2.f, -2.f} * r + (v2f){1.f, 1.f};  // t = 1 - 2/(e^2v+1)
}

// P(t) for the dim-pair: 8 v_pk_fma_f32
__device__ __forceinline__ v2f horner9v(v2f t, const v2f* a) {
    v2f p = a[8];
#pragma unroll
    for (int j = 7; j >= 0; --j) p = p * t + a[j];
    return p;
}

__global__ __launch_bounds__(THREADS, 8)   // force VGPR<=64 -> 8 waves/SIMD
void kan_kernel(const float* __restrict__ x,
                const float* __restrict__ coef,
                const float* __restrict__ hw,
                float* __restrict__ out)
{
    const int tid  = threadIdx.x;
    const int lane = tid & 63;
    const int wave = tid >> 6;
    const int d0   = tid * 2;          // this thread owns dims d0, d0+1

    // ---- 18 Chebyshev coefs (dim-major, 9/dim) -> packed monomial a2[9] ----
    v2f a2[9];
    {
        float cf[18];
        const float2* cp = (const float2*)(coef + (size_t)d0 * 9); // 72B offset, 8B aligned
#pragma unroll
        for (int i = 0; i < 9; ++i) {
            float2 v = cp[i];
            cf[2 * i + 0] = v.x;
            cf[2 * i + 1] = v.y;
        }
        v2f c[9];
#pragma unroll
        for (int k = 0; k < 9; ++k)
            c[k] = (v2f){cf[k], cf[9 + k]};   // {dim d0 coef k, dim d0+1 coef k}
        a2[0] = ((c[0] - c[2]) + (c[4] - c[6])) + c[8];
        a2[1] = c[1] - 3.f*c[3] + 5.f*c[5] - 7.f*c[7];
        a2[2] = 2.f*c[2] - 8.f*c[4] + 18.f*c[6] - 32.f*c[8];
        a2[3] = 4.f*c[3] - 20.f*c[5] + 56.f*c[7];
        a2[4] = 8.f*c[4] - 48.f*c[6] + 160.f*c[8];
        a2[5] = 16.f*c[5] - 112.f*c[7];
        a2[6] = 32.f*c[6] - 256.f*c[8];
        a2[7] = 64.f*c[7];
        a2[8] = 128.f*c[8];
    }

    const int row0 = blockIdx.x * ROWS_PER_BLOCK;

    // ---- issue ALL 8 row loads (8B/lane, coalesced, 8 outstanding) ----
    float2 xv[ROWS_PER_BLOCK];
#pragma unroll
    for (int r = 0; r < ROWS_PER_BLOCK; ++r)
        xv[r] = *(const float2*)(x + (size_t)(row0 + r) * DIMS + d0);

    float s[ROWS_PER_BLOCK];
#pragma unroll
    for (int r = 0; r < ROWS_PER_BLOCK; ++r) {
        v2f v = {xv[r].x, xv[r].y};
        v2f q = horner9v(tanh2(v), a2);
        s[r] = q.x + q.y;
    }

    // ---- 4 interleaved packed butterflies over 64 lanes ----
    v2f u = {s[0], s[1]}, w = {s[2], s[3]}, y = {s[4], s[5]}, z = {s[6], s[7]};
#pragma unroll
    for (int off = 32; off >= 1; off >>= 1) {
        v2f us = { __shfl_xor(u.x, off, 64), __shfl_xor(u.y, off, 64) };
        v2f ws = { __shfl_xor(w.x, off, 64), __shfl_xor(w.y, off, 64) };
        v2f ys = { __shfl_xor(y.x, off, 64), __shfl_xor(y.y, off, 64) };
        v2f zs = { __shfl_xor(z.x, off, 64), __shfl_xor(z.y, off, 64) };
        u += us; w += ws; y += ys; z += zs;
    }

    __shared__ float part[NWAVES][ROWS_PER_BLOCK];
    if (lane == 0) {
        part[wave][0] = u.x; part[wave][1] = u.y;
        part[wave][2] = w.x; part[wave][3] = w.y;
        part[wave][4] = y.x; part[wave][5] = y.y;
        part[wave][6] = z.x; part[wave][7] = z.y;
    }
    __syncthreads();

    if (tid < ROWS_PER_BLOCK) {
        float v = 0.f;
#pragma unroll
        for (int wv = 0; wv < NWAVES; ++wv) v += part[wv][tid];
        out[row0 + tid] = hw[0] * v;
    }
}

extern "C" void kernel_launch(void* const* d_in, const int* in_sizes, int n_in,
                              void* d_out, int out_size, void* d_ws, size_t ws_size,
                              hipStream_t stream) {
    const float* x    = (const float*)d_in[0];
    const float* coef = (const float*)d_in[1];
    const float* hw   = (const float*)d_in[2];
    // d_in[3] is `degree` (int32) == 8, hard-coded.
    float* out = (float*)d_out;
    kan_kernel<<<NBLOCKS, THREADS, 0, stream>>>(x, coef, hw, out);
}